// Round 7
// baseline (77.888 us; speedup 1.0000x reference)
//
#include <hip/hip_runtime.h>

#define HW_TOTAL (4096 * 4096)
#define NBINS 256
#define NCHUNK (HW_TOTAL / 4)      // int4 chunks = 4M
#define GRID_B 256                 // 1 block per CU -> all co-resident (no deadlock)
#define BLK 1024                   // 16 waves
#define BATCH 16                   // int4 chunks per thread, in 2 halves of 8
#define HALF 8
// 256 blocks * 1024 threads * 16 chunks = 4M chunks exactly.

typedef int int4n __attribute__((ext_vector_type(4)));               // aligned 16
typedef int int4a __attribute__((ext_vector_type(4), aligned(4)));   // dword-aligned

// ws (u32 words): [0..255] ghist, [256] ticket, [257] flag (= thresh+1)
#define WS_WORDS 258
#define WS_NEED (WS_WORDS * 4)

// ---------------------------------------------------------------------------
// Fused single-dispatch Otsu. Phase A: LDS hist (bank-interleaved 4 sub-hists)
// + global atomic flush. Handshake: device-scope ticket; LAST block computes
// the threshold (1 KiB read + wave scan) and publishes thresh+1 via a release
// store; all other blocks spin (thread 0, s_sleep backoff). Phase C: each
// block binarizes its own (L2-warm) chunk; unaligned dwordx4 loads realize
// the +1 output shift, stores stay 16 B aligned nontemporal.
// ---------------------------------------------------------------------------
__global__ __launch_bounds__(BLK, 4) void otsu_fused_k(const int* __restrict__ img,
                                                       int* __restrict__ out,
                                                       unsigned* __restrict__ ws) {
    __shared__ unsigned h[4 * NBINS];
    __shared__ int s_thresh;
    __shared__ unsigned s_islast;

    const int t = threadIdx.x;
    const int b = blockIdx.x;
    const int4* img4 = (const int4*)img;

    for (int i = t; i < 4 * NBINS; i += BLK) h[i] = 0;
    __syncthreads();

    // ---------------- Phase A: histogram ----------------
    unsigned* hp = h + (t & 3);            // sub-histogram base (4-bank interleave)
    const int wave = t >> 6, lane = t & 63;
    const int i0 = b * (BLK * BATCH) + wave * (64 * BATCH) + lane;

#pragma unroll
    for (int half = 0; half < BATCH / HALF; ++half) {
        int4 v[HALF];
        const int j0 = i0 + half * (HALF * 64);
#pragma unroll
        for (int k = 0; k < HALF; ++k) v[k] = img4[j0 + k * 64];
#pragma unroll
        for (int k = 0; k < HALF; ++k) {
            atomicAdd(&hp[((unsigned)v[k].x) << 2], 1u);
            atomicAdd(&hp[((unsigned)v[k].y) << 2], 1u);
            atomicAdd(&hp[((unsigned)v[k].z) << 2], 1u);
            atomicAdd(&hp[((unsigned)v[k].w) << 2], 1u);
        }
    }
    __syncthreads();

    if (t < NBINS) {
        unsigned s = h[t << 2] + h[(t << 2) | 1] + h[(t << 2) | 2] + h[(t << 2) | 3];
        atomicAdd(&ws[t], s);              // device-scope flush into ghist
    }
    __syncthreads();                       // compiler drains vmcnt before barrier

    // ---------------- Handshake: ticket, last block computes threshold ------
    if (t == 0) {
        __threadfence();
        unsigned my = __hip_atomic_fetch_add(&ws[256], 1u, __ATOMIC_ACQ_REL,
                                             __HIP_MEMORY_SCOPE_AGENT);
        s_islast = (my == GRID_B - 1) ? 1u : 0u;
    }
    __syncthreads();

    if (s_islast) {
        if (t < NBINS)
            h[t] = __hip_atomic_load(&ws[t], __ATOMIC_RELAXED, __HIP_MEMORY_SCOPE_AGENT);
        __syncthreads();
        if (t < 64) {
            uint4 c4 = ((const uint4*)h)[t];
            unsigned cs[4] = {c4.x, c4.y, c4.z, c4.w};

            unsigned long long lc[4], lv[4];
            unsigned long long ccum = 0ull, vcum = 0ull;
#pragma unroll
            for (int k = 0; k < 4; ++k) {
                ccum += cs[k];
                vcum += (unsigned long long)cs[k] * (unsigned)(4 * t + k);
                lc[k] = ccum;
                lv[k] = vcum;
            }
            unsigned long long cscan = ccum, vscan = vcum;
            for (int d = 1; d < 64; d <<= 1) {
                unsigned long long cu = __shfl_up(cscan, d);
                unsigned long long vu = __shfl_up(vscan, d);
                if (t >= d) { cscan += cu; vscan += vu; }
            }
            const unsigned long long cbase = cscan - ccum;
            const unsigned long long vbase = vscan - vcum;
            const unsigned long long vtotal = __shfl(vscan, 63);

            double best = -1.0;
            int bestt = 255;
            const double hw = (double)HW_TOTAL;
            const double vtot_d = (double)vtotal;
#pragma unroll
            for (int k = 0; k < 4; ++k) {
                int tt = 4 * t + k;
                if (tt > 254) continue;
                double nb = (double)(cbase + lc[k]);
                double sb = (double)(vbase + lv[k]);
                double nw = hw - nb;
                double sw = vtot_d - sb;
                double dm = sb / nb - sw / nw;
                double var = nb * nw * dm * dm;
                if (var > best || (var == best && tt < bestt)) { best = var; bestt = tt; }
            }
            for (int d = 32; d >= 1; d >>= 1) {
                double ov = __shfl_xor(best, d);
                int ot = __shfl_xor(bestt, d);
                if (ov > best || (ov == best && ot < bestt)) { best = ov; bestt = ot; }
            }
            if (t == 0) {
                out[0] = bestt;
                s_thresh = bestt;
                __hip_atomic_store(&ws[257], (unsigned)bestt + 1u, __ATOMIC_RELEASE,
                                   __HIP_MEMORY_SCOPE_AGENT);
            }
        }
    } else if (t == 0) {
        unsigned f;
        while ((f = __hip_atomic_load(&ws[257], __ATOMIC_ACQUIRE,
                                      __HIP_MEMORY_SCOPE_AGENT)) == 0u)
            __builtin_amdgcn_s_sleep(8);
        s_thresh = (int)f - 1;
    }
    __syncthreads();
    const int thresh = s_thresh;

    // ---------------- Phase C: binarize own chunk ----------------
#pragma unroll
    for (int half = 0; half < BATCH / HALF; ++half) {
        const int j0 = i0 + half * (HALF * 64);
#pragma unroll
        for (int k = 0; k < HALF; ++k) {
            const int c = j0 + k * 64;
            int4a v = *(const int4a*)(img + (c ? 4 * c - 1 : 0));  // pixels 4c-1..4c+2
            int4n o;
            o.x = (v.x <= thresh) ? 0 : 256;
            o.y = (v.y <= thresh) ? 0 : 256;
            o.z = (v.z <= thresh) ? 0 : 256;
            o.w = (v.w <= thresh) ? 0 : 256;
            if (c == 0) { o.w = o.z; o.z = o.y; o.y = o.x; o.x = thresh; }
            __builtin_nontemporal_store(o, (int4n*)out + c);
        }
    }
    if (i0 == 0)
        out[HW_TOTAL] = (img[HW_TOTAL - 1] <= thresh) ? 0 : 256;
}

// ---------------------------------------------------------------------------
// Fallback (ws too small — not expected): 3-dispatch scheme from round 6.
// ---------------------------------------------------------------------------
__global__ __launch_bounds__(BLK, 4) void fb_hist_k(const int4* __restrict__ img4,
                                                    unsigned* __restrict__ ghist) {
    __shared__ unsigned h[4 * NBINS];
    const int t = threadIdx.x;
    for (int i = t; i < 4 * NBINS; i += BLK) h[i] = 0;
    __syncthreads();
    unsigned* hp = h + (t & 3);
    const int wave = t >> 6, lane = t & 63;
    const int i0 = blockIdx.x * (BLK * BATCH) + wave * (64 * BATCH) + lane;
#pragma unroll
    for (int half = 0; half < BATCH / HALF; ++half) {
        int4 v[HALF];
        const int j0 = i0 + half * (HALF * 64);
#pragma unroll
        for (int k = 0; k < HALF; ++k) v[k] = img4[j0 + k * 64];
#pragma unroll
        for (int k = 0; k < HALF; ++k) {
            atomicAdd(&hp[((unsigned)v[k].x) << 2], 1u);
            atomicAdd(&hp[((unsigned)v[k].y) << 2], 1u);
            atomicAdd(&hp[((unsigned)v[k].z) << 2], 1u);
            atomicAdd(&hp[((unsigned)v[k].w) << 2], 1u);
        }
    }
    __syncthreads();
    if (t < NBINS) {
        unsigned s = h[t << 2] + h[(t << 2) | 1] + h[(t << 2) | 2] + h[(t << 2) | 3];
        if (s) atomicAdd(&ghist[t], s);
    }
}

__global__ __launch_bounds__(64) void fb_thresh_k(const unsigned* __restrict__ cnt,
                                                  int* __restrict__ d_out,
                                                  unsigned* __restrict__ ws) {
    const int lane = threadIdx.x;
    uint4 c4 = ((const uint4*)cnt)[lane];
    unsigned cs[4] = {c4.x, c4.y, c4.z, c4.w};
    unsigned long long lc[4], lv[4], ccum = 0ull, vcum = 0ull;
#pragma unroll
    for (int k = 0; k < 4; ++k) {
        ccum += cs[k];
        vcum += (unsigned long long)cs[k] * (unsigned)(4 * lane + k);
        lc[k] = ccum; lv[k] = vcum;
    }
    unsigned long long cscan = ccum, vscan = vcum;
    for (int d = 1; d < 64; d <<= 1) {
        unsigned long long cu = __shfl_up(cscan, d);
        unsigned long long vu = __shfl_up(vscan, d);
        if (lane >= d) { cscan += cu; vscan += vu; }
    }
    const unsigned long long cbase = cscan - ccum, vbase = vscan - vcum;
    const unsigned long long vtotal = __shfl(vscan, 63);
    double best = -1.0; int bestt = 255;
#pragma unroll
    for (int k = 0; k < 4; ++k) {
        int tt = 4 * lane + k;
        if (tt > 254) continue;
        double nb = (double)(cbase + lc[k]), sb = (double)(vbase + lv[k]);
        double nw = (double)HW_TOTAL - nb, sw = (double)vtotal - sb;
        double dm = sb / nb - sw / nw;
        double var = nb * nw * dm * dm;
        if (var > best || (var == best && tt < bestt)) { best = var; bestt = tt; }
    }
    for (int d = 32; d >= 1; d >>= 1) {
        double ov = __shfl_xor(best, d);
        int ot = __shfl_xor(bestt, d);
        if (ov > best || (ov == best && ot < bestt)) { best = ov; bestt = ot; }
    }
    if (lane == 0) { d_out[0] = bestt; ws[257] = (unsigned)bestt + 1u; }
}

__global__ __launch_bounds__(BLK, 4) void fb_bin_k(const int* __restrict__ img,
                                                   int* __restrict__ out,
                                                   const unsigned* __restrict__ ws) {
    const int thresh = (int)ws[257] - 1;
    const int t = threadIdx.x;
    const int wave = t >> 6, lane = t & 63;
    const int i0 = blockIdx.x * (BLK * BATCH) + wave * (64 * BATCH) + lane;
#pragma unroll
    for (int half = 0; half < BATCH / HALF; ++half) {
        const int j0 = i0 + half * (HALF * 64);
#pragma unroll
        for (int k = 0; k < HALF; ++k) {
            const int c = j0 + k * 64;
            int4a v = *(const int4a*)(img + (c ? 4 * c - 1 : 0));
            int4n o;
            o.x = (v.x <= thresh) ? 0 : 256;
            o.y = (v.y <= thresh) ? 0 : 256;
            o.z = (v.z <= thresh) ? 0 : 256;
            o.w = (v.w <= thresh) ? 0 : 256;
            if (c == 0) { o.w = o.z; o.z = o.y; o.y = o.x; o.x = thresh; }
            __builtin_nontemporal_store(o, (int4n*)out + c);
        }
    }
    if (i0 == 0)
        out[HW_TOTAL] = (img[HW_TOTAL - 1] <= thresh) ? 0 : 256;
}

extern "C" void kernel_launch(void* const* d_in, const int* in_sizes, int n_in,
                              void* d_out, int out_size, void* d_ws, size_t ws_size,
                              hipStream_t stream) {
    const int* img = (const int*)d_in[0];
    int* out = (int*)d_out;
    unsigned* ws = (unsigned*)d_ws;

    // zero ghist + ticket + flag every call (no reliance on cross-call state)
    (void)hipMemsetAsync(ws, 0, WS_NEED, stream);

    if (ws_size >= (size_t)WS_NEED) {
        otsu_fused_k<<<GRID_B, BLK, 0, stream>>>(img, out, ws);
    } else {
        fb_hist_k<<<GRID_B, BLK, 0, stream>>>((const int4*)img, ws);
        fb_thresh_k<<<1, 64, 0, stream>>>(ws, out, ws);
        fb_bin_k<<<GRID_B, BLK, 0, stream>>>(img, out, ws);
    }
}